// Round 3
// baseline (511.580 us; speedup 1.0000x reference)
//
#include <hip/hip_runtime.h>

#define B_   512
#define C_   256
#define HWD_ 384
#define TS   132   // T32 row stride in words: 132 ≡ 0 mod 4 -> 16-B aligned b128 rows,
                   // stage-2 bank = (4k + n) % 32 -> 2-way max (free, m136)

typedef __bf16 bf16x8 __attribute__((ext_vector_type(8)));
typedef float  f32x4  __attribute__((ext_vector_type(4)));

// ---------------- kernel 1: per-(b,c) mean over HWD=384 (proven R1) ----------------
__global__ __launch_bounds__(256) void mean_kernel(const float* __restrict__ x,
                                                   float* __restrict__ cadj) {
    const int row  = (blockIdx.x << 2) + (threadIdx.x >> 6);
    const int lane = threadIdx.x & 63;
    const float2* p = (const float2*)(x + (size_t)row * HWD_);
    float s = 0.f;
#pragma unroll
    for (int t = 0; t < 3; ++t) {
        float2 v = p[lane + (t << 6)];
        s += v.x + v.y;
    }
#pragma unroll
    for (int off = 32; off; off >>= 1) s += __shfl_xor(s, off, 64);
    if (lane == 0) cadj[row] = s * (1.0f / HWD_);
}

// ---------------- kernel 2: fused  out = relu( ((adj .* s_b) @ fea_b) * para )
// 128x128 tile, K=256 in 8 chunks of 32. One barrier per chunk (software pipeline).
// B: float4 global -> T32 (fp32, dbuf) -> transpose -> Bsf (bf16 frag chunks, dbuf).
// A: consumer-register path (adj loads L2-hot + on-the-fly s), zero LDS.
__global__ __launch_bounds__(256, 2) void gemm_kernel(const float* __restrict__ x,
                                                      const float* __restrict__ adj,
                                                      const float* __restrict__ para,
                                                      const float* __restrict__ cadj,
                                                      float* __restrict__ out) {
    const int mt = blockIdx.x;   // 0..1
    const int nt = blockIdx.y;   // 0..2
    const int b  = blockIdx.z;   // 0..511
    const int i0 = mt * 128, n0 = nt * 128;

    const int t = threadIdx.x, lane = t & 63, w = t >> 6;
    const int wm = w & 1, wn = w >> 1;
    const int lm = lane & 15, quad = lane >> 4;

    __shared__ float  sca[C_];                 // 1 KB: this batch's channel means
    __shared__ float  T32[2][32 * TS];         // 33 KB: fp32 x-tile, double-buffered
    __shared__ __bf16 Bsf[2][8 * 64 * 8];      // 16 KB: bf16 B fragment chunks, dbuf

    sca[t] = cadj[b * C_ + t];

    // --- B global-load mapping: thread -> (k-row r + 8p, float4 col g) ---
    const int br = t >> 5;         // 0..7
    const int bg = t & 31;         // 0..31 -> n-offset 4*bg
    const float* xbase = x + (size_t)b * C_ * HWD_ + n0 + 4 * bg;

    // --- stage-2 (transpose) mapping: thread -> (frag chunk c, k-half h, n lane lm2) ---
    const int s2c = t >> 5, s2h = (t >> 4) & 1, s2lm = t & 15;
    const int s2n = s2c * 16 + s2lm;

    f32x4 acc[4][4];
#pragma unroll
    for (int mm = 0; mm < 4; ++mm)
#pragma unroll
        for (int nn = 0; nn < 4; ++nn)
            acc[mm][nn] = (f32x4){0.f, 0.f, 0.f, 0.f};

    // ---- prologue: chunk0 -> T32[0]; prefetch chunk1 into greg ----
    float4 greg[4];
#pragma unroll
    for (int p = 0; p < 4; ++p)
        greg[p] = *(const float4*)(xbase + (size_t)(br + 8 * p) * HWD_);
#pragma unroll
    for (int p = 0; p < 4; ++p)
        *(float4*)&T32[0][(br + 8 * p) * TS + 4 * bg] = greg[p];
#pragma unroll
    for (int p = 0; p < 4; ++p)
        greg[p] = *(const float4*)(xbase + (size_t)(32 + br + 8 * p) * HWD_);
    __syncthreads();

    float ca_i[4];
#pragma unroll
    for (int mm = 0; mm < 4; ++mm) ca_i[mm] = sca[i0 + wm * 64 + mm * 16 + lm];

#pragma unroll
    for (int q = 0; q <= 8; ++q) {
        // ---- stage 2: T32[q&1] -> Bsf[q&1] (fp32 -> bf16 transpose) ----
        if (q < 8) {
            float v[16];
#pragma unroll
            for (int j2 = 0; j2 < 16; ++j2)
                v[j2] = T32[q & 1][(s2h * 16 + j2) * TS + s2n];
            bf16x8 p0, p1;
#pragma unroll
            for (int j = 0; j < 8; ++j) { p0[j] = (__bf16)v[j]; p1[j] = (__bf16)v[8 + j]; }
            *(bf16x8*)&Bsf[q & 1][(s2c * 64 + (2 * s2h) * 16 + s2lm) * 8]     = p0;
            *(bf16x8*)&Bsf[q & 1][(s2c * 64 + (2 * s2h + 1) * 16 + s2lm) * 8] = p1;
        }
        // ---- stage 1: write prefetched chunk q+1 into T32[(q+1)&1] ----
        if (q + 1 < 8) {
#pragma unroll
            for (int p = 0; p < 4; ++p)
                *(float4*)&T32[(q + 1) & 1][(br + 8 * p) * TS + 4 * bg] = greg[p];
        }
        // ---- prefetch chunk q+2 into greg ----
        if (q + 2 < 8) {
#pragma unroll
            for (int p = 0; p < 4; ++p)
                greg[p] = *(const float4*)(xbase + (size_t)((q + 2) * 32 + br + 8 * p) * HWD_);
        }
        // ---- consume chunk q-1: A-frags in registers + MFMA ----
        if (q >= 1) {
            const int kc = q - 1;
            f32x4 ck0 = *(const f32x4*)&sca[kc * 32 + quad * 8];
            f32x4 ck1 = *(const f32x4*)&sca[kc * 32 + quad * 8 + 4];
            bf16x8 af[4];
#pragma unroll
            for (int mm = 0; mm < 4; ++mm) {
                const float* ap = adj + (size_t)(i0 + wm * 64 + mm * 16 + lm) * C_ + kc * 32 + quad * 8;
                float4 a0 = *(const float4*)ap;
                float4 a1 = *(const float4*)(ap + 4);
#pragma unroll
                for (int j = 0; j < 8; ++j) {
                    float ck = (j < 4) ? ck0[j] : ck1[j - 4];
                    float d  = ck - ca_i[mm];
                    float e  = __expf(-fabsf(d));
                    float s  = 2.f * e * __builtin_amdgcn_rcpf(1.f + e);
                    float av = (j < 4) ? (&a0.x)[j] : (&a1.x)[j - 4];
                    af[mm][j] = (__bf16)(av * s);
                }
            }
            bf16x8 bfr[4];
#pragma unroll
            for (int nn = 0; nn < 4; ++nn)
                bfr[nn] = *(const bf16x8*)&Bsf[kc & 1][((wn * 4 + nn) * 64 + lane) * 8];
#pragma unroll
            for (int mm = 0; mm < 4; ++mm)
#pragma unroll
                for (int nn = 0; nn < 4; ++nn)
                    acc[mm][nn] = __builtin_amdgcn_mfma_f32_16x16x32_bf16(
                        af[mm], bfr[nn], acc[mm][nn], 0, 0, 0);
        }
        if (q < 8) __syncthreads();
    }

    // ---- epilogue: *para, relu, store (R1-verified) ----
#pragma unroll
    for (int mm = 0; mm < 4; ++mm) {
#pragma unroll
        for (int r = 0; r < 4; ++r) {
            const int i = i0 + wm * 64 + mm * 16 + quad * 4 + r;
            const float* pp = para + (size_t)i * HWD_;
            float* op = out + ((size_t)b * C_ + i) * HWD_;
#pragma unroll
            for (int nn = 0; nn < 4; ++nn) {
                const int n = n0 + wn * 64 + nn * 16 + lm;
                float v = acc[mm][nn][r] * pp[n];
                op[n] = v > 0.f ? v : 0.f;
            }
        }
    }
}

extern "C" void kernel_launch(void* const* d_in, const int* in_sizes, int n_in,
                              void* d_out, int out_size, void* d_ws, size_t ws_size,
                              hipStream_t stream) {
    const float* x    = (const float*)d_in[0];
    const float* adj  = (const float*)d_in[1];
    const float* para = (const float*)d_in[2];
    float* out  = (float*)d_out;
    float* cadj = (float*)d_ws;   // 512 KB

    mean_kernel<<<dim3((B_ * C_) / 4), 256, 0, stream>>>(x, cadj);
    gemm_kernel<<<dim3(2, 3, B_), 256, 0, stream>>>(x, adj, para, cadj, out);
}